// Round 2
// baseline (724.755 us; speedup 1.0000x reference)
//
#include <hip/hip_runtime.h>
#include <hip/hip_bf16.h>

#define WIDTH_ 2560
#define LRU_   2560
#define HEADS_ 8
#define BW_    320
#define DCONV_ 4
#define BB     4
#define LL     2048
#define MROWS  (BB*LL)          // 8192
#define NCH    32               // scan chunks
#define CLEN   (LL/NCH)         // 64

typedef unsigned short ushort_t;
typedef __attribute__((ext_vector_type(8))) short short8;
typedef __attribute__((ext_vector_type(4))) float f32x4;

__device__ __forceinline__ unsigned short f2bf(float f) {
  union { float f; unsigned u; } v; v.f = f;
  unsigned r = v.u + 0x7fffu + ((v.u >> 16) & 1u);
  return (unsigned short)(r >> 16);
}
__device__ __forceinline__ float bf2f(unsigned short h) {
  union { unsigned u; float f; } v; v.u = ((unsigned)h) << 16;
  return v.f;
}
__device__ __forceinline__ void async_load16(const void* g, void* l) {
  __builtin_amdgcn_global_load_lds(
      (const __attribute__((address_space(1))) unsigned*)g,
      (__attribute__((address_space(3))) unsigned*)l, 16, 0, 0);
}
__device__ __forceinline__ float sigmoidf_(float x) {
  return 1.f / (1.f + __expf(-x));
}

// ---------------- conversion kernels ----------------
__global__ void cvt_bf16x4(const float4* __restrict__ in, ushort4* __restrict__ out, int n4) {
  int i = blockIdx.x * blockDim.x + threadIdx.x;
  if (i >= n4) return;
  float4 v = in[i];
  ushort4 o;
  o.x = f2bf(v.x); o.y = f2bf(v.y); o.z = f2bf(v.z); o.w = f2bf(v.w);
  out[i] = o;
}

// wT[h][j][i] = w[h][i][j]   (bf16)
__global__ void cvt_transpose(const float* __restrict__ w, ushort_t* __restrict__ wT, int n) {
  int i = blockIdx.x * blockDim.x + threadIdx.x;
  if (i >= n) return;
  int ii = i % BW_;
  int j  = (i / BW_) % BW_;
  int h  = i / (BW_ * BW_);
  wT[i] = f2bf(w[(h * BW_ + ii) * BW_ + j]);
}

// ctab[e] = -8 * softplus(a_param[e])
__global__ void ctab_kernel(const float* __restrict__ apar, float* __restrict__ ctab) {
  int e = blockIdx.x * blockDim.x + threadIdx.x;
  if (e >= LRU_) return;
  float ap = apar[e];
  float sp = (ap > 15.f) ? ap : log1pf(expf(ap));
  ctab[e] = -8.f * sp;
}

// ---------------- GEMM: C[M,N] = A[M,K](bf16) * B[N,K](bf16)^T ----------------
// EPI: 0=f32 store (+bias), 1=bf16 store (+bias), 2=gate-x (xc*sigmoid), 3=gate-a (a)
template<int BN, int EPI>
__global__ __launch_bounds__(256, 2)
void gemm_bt(const ushort_t* __restrict__ A, int lda, int aBatch,
             const ushort_t* __restrict__ B, int bBatch,
             void* __restrict__ Cv, int ldc, int cBatch,
             const float* __restrict__ bias, int biasBatch,
             int K,
             const ushort_t* __restrict__ xcsrc,
             const float* __restrict__ ctab,
             const int* __restrict__ seg) {
  constexpr int BM = 128, BK = 32;
  constexpr int WTN = BN / 2;
  constexpr int NF = WTN / 16;
  constexpr int A_ISS = (BM * BK * 2) / (256 * 16);
  constexpr int B_ISS = (BN * BK * 2) / (256 * 16);

  __shared__ ushort_t lds_a[BM * BK];
  __shared__ ushort_t lds_b[BN * BK];

  const int tid = threadIdx.x;
  const int w = tid >> 6, lane = tid & 63;
  const int wr = w >> 1, wc = w & 1;
  const int tm = blockIdx.x * BM;
  const int tn = blockIdx.y * BN;
  const int z = blockIdx.z;
  const ushort_t* Ab = A + (size_t)z * aBatch;
  const ushort_t* Bb = B + (size_t)z * bBatch + (size_t)tn * K;

  f32x4 acc[4][NF] = {};

  const int ksub = (lane >> 4) * 8;
  const int rA = wr * 64 + (lane & 15);
  const int rB = wc * WTN + (lane & 15);

  for (int k0 = 0; k0 < K; k0 += BK) {
#pragma unroll
    for (int i = 0; i < A_ISS; ++i) {
      int bo = (i * 256 + tid) * 16;
      int row = bo >> 6, colb = bo & 63;
      async_load16((const char*)Ab + (size_t)(tm + row) * lda * 2 + (size_t)k0 * 2 + colb,
                   (char*)lds_a + bo);
    }
#pragma unroll
    for (int i = 0; i < B_ISS; ++i) {
      int bo = (i * 256 + tid) * 16;
      int row = bo >> 6, colb = bo & 63;
      async_load16((const char*)Bb + (size_t)row * K * 2 + (size_t)k0 * 2 + colb,
                   (char*)lds_b + bo);
    }
    __syncthreads();

    short8 af[4], bfr[NF];
#pragma unroll
    for (int mf = 0; mf < 4; ++mf)
      af[mf] = *(const short8*)&lds_a[(rA + mf * 16) * BK + ksub];
#pragma unroll
    for (int nf = 0; nf < NF; ++nf)
      bfr[nf] = *(const short8*)&lds_b[(rB + nf * 16) * BK + ksub];
#pragma unroll
    for (int mf = 0; mf < 4; ++mf)
#pragma unroll
      for (int nf = 0; nf < NF; ++nf)
        acc[mf][nf] = __builtin_amdgcn_mfma_f32_16x16x32_bf16(af[mf], bfr[nf], acc[mf][nf], 0, 0, 0);
    __syncthreads();
  }

  // epilogue: C row = (lane>>4)*4 + r, col = lane&15  [m89-verified]
  const int crow0 = tm + wr * 64 + ((lane >> 4) << 2);
  const int ccol0 = tn + wc * WTN + (lane & 15);
#pragma unroll
  for (int mf = 0; mf < 4; ++mf) {
#pragma unroll
    for (int nf = 0; nf < NF; ++nf) {
      const int col = ccol0 + nf * 16;
      const float bv = bias ? bias[z * biasBatch + col] : 0.f;
#pragma unroll
      for (int r = 0; r < 4; ++r) {
        const int row = crow0 + mf * 16 + r;
        const float v = acc[mf][nf][r] + bv;
        if (EPI == 0) {
          float* C = (float*)Cv + (size_t)z * cBatch;
          C[(size_t)row * ldc + col] = v;
        } else if (EPI == 1) {
          ushort_t* C = (ushort_t*)Cv + (size_t)z * cBatch;
          C[(size_t)row * ldc + col] = f2bf(v);
        } else if (EPI == 2) {
          // GX = xc * sigmoid(logit)
          ushort_t* C = (ushort_t*)Cv + (size_t)z * cBatch;
          float xc = bf2f(xcsrc[(size_t)row * ldc + (size_t)z * cBatch + col]);
          C[(size_t)row * ldc + col] = f2bf(xc * sigmoidf_(v));
        } else {
          // a = reset ? 0 : exp(c * sigmoid(logit))
          ushort_t* C = (ushort_t*)Cv + (size_t)z * cBatch;
          float ga = sigmoidf_(v);
          float la = ctab[(size_t)z * cBatch + col] * ga;
          float a = (seg[row] == 0) ? 0.f : expf(la);
          C[(size_t)row * ldc + col] = f2bf(a);
        }
      }
    }
  }
}

// ---------------- conv (causal depthwise, window 4), bf16 in/out ----------------
__global__ void conv_kernel(const ushort_t* __restrict__ xl, const float* __restrict__ convw,
                            const float* __restrict__ convb, ushort_t* __restrict__ xcbf) {
  int i = blockIdx.x * blockDim.x + threadIdx.x;
  if (i >= MROWS * LRU_) return;
  int e = i % LRU_;
  int t = (i / LRU_) % LL;
  int b = i / (LRU_ * LL);
  float4 wv = ((const float4*)convw)[e];
  float acc = convb[e];
  const ushort_t* base = xl + ((size_t)b * LL) * LRU_ + e;
  if (t >= 3) acc += wv.x * bf2f(base[(size_t)(t - 3) * LRU_]);
  if (t >= 2) acc += wv.y * bf2f(base[(size_t)(t - 2) * LRU_]);
  if (t >= 1) acc += wv.z * bf2f(base[(size_t)(t - 1) * LRU_]);
  acc += wv.w * bf2f(base[(size_t)t * LRU_]);
  xcbf[i] = f2bf(acc);
}

__global__ void conv_state_kernel(const ushort_t* __restrict__ xl, const int* __restrict__ cidx,
                                  float* __restrict__ cs) {
  int i = blockIdx.x * blockDim.x + threadIdx.x;
  if (i >= BB * LRU_ * DCONV_) return;
  int e = (i / DCONV_) % LRU_;
  int b = i / (DCONV_ * LRU_);
  int idx = cidx[i];           // index into padded time axis (len L+3)
  int ts = idx - (DCONV_ - 1);
  float v = 0.f;
  if (ts >= 0 && ts < LL) v = bf2f(xl[((size_t)b * LL + ts) * LRU_ + e]);
  cs[i] = v;
}

// ---------------- chunked scan (a, nx derived from AA, GX) ----------------
__global__ void scanA(const ushort_t* __restrict__ AA, const ushort_t* __restrict__ GX,
                      float* __restrict__ cA, float* __restrict__ cH) {
  int i = blockIdx.x * blockDim.x + threadIdx.x;
  if (i >= BB * NCH * LRU_) return;
  int e = i % LRU_;
  int c = (i / LRU_) % NCH;
  int b = i / (LRU_ * NCH);
  float Ap = 1.f, h = 0.f;
  size_t base = ((size_t)b * LL + (size_t)c * CLEN) * LRU_ + e;
  for (int t = 0; t < CLEN; ++t) {
    size_t j = base + (size_t)t * LRU_;
    float a = bf2f(AA[j]);
    float nx = bf2f(GX[j]) * sqrtf(fmaxf(0.f, 1.f - a * a));
    Ap *= a;
    h = a * h + nx;
  }
  cA[i] = Ap; cH[i] = h;
}

__global__ void scanB(const float* __restrict__ cA, const float* __restrict__ cH,
                      float* __restrict__ hInit) {
  int i = blockIdx.x * blockDim.x + threadIdx.x;
  if (i >= BB * LRU_) return;
  int e = i % LRU_;
  int b = i / LRU_;
  float h = 0.f;
  for (int c = 0; c < NCH; ++c) {
    size_t j = ((size_t)b * NCH + c) * LRU_ + e;
    hInit[j] = h;
    h = cA[j] * h + cH[j];
  }
}

__global__ void scanC(const ushort_t* __restrict__ AA, const ushort_t* __restrict__ GXpre,
                      const float* __restrict__ hInit, const ushort_t* __restrict__ ybf,
                      const float* __restrict__ ybias, float* __restrict__ lastH) {
  int i = blockIdx.x * blockDim.x + threadIdx.x;
  if (i >= BB * NCH * LRU_) return;
  int e = i % LRU_;
  int c = (i / LRU_) % NCH;
  int b = i / (LRU_ * NCH);
  float h = hInit[i];
  float yb = ybias[e];
  ushort_t* pre = (ushort_t*)GXpre;   // in-place: read GX[j], write pre[j]
  size_t base = ((size_t)b * LL + (size_t)c * CLEN) * LRU_ + e;
  for (int t = 0; t < CLEN; ++t) {
    size_t j = base + (size_t)t * LRU_;
    float a = bf2f(AA[j]);
    float nx = bf2f(GXpre[j]) * sqrtf(fmaxf(0.f, 1.f - a * a));
    h = a * h + nx;
    float yv = bf2f(ybf[j]) + yb;
    float g = 0.5f * yv * (1.f + erff(yv * 0.70710678118f));
    pre[j] = f2bf(h * g);
  }
  if (c == NCH - 1) lastH[(size_t)b * LRU_ + e] = h;
}

// ---------------- launch ----------------
extern "C" void kernel_launch(void* const* d_in, const int* in_sizes, int n_in,
                              void* d_out, int out_size, void* d_ws, size_t ws_size,
                              hipStream_t stream) {
  const float* x     = (const float*)d_in[0];
  const int*   seg   = (const int*)d_in[1];
  const int*   cidx  = (const int*)d_in[2];
  const float* Wx    = (const float*)d_in[3];
  const float* bx    = (const float*)d_in[4];
  const float* Wy    = (const float*)d_in[5];
  const float* convw = (const float*)d_in[6];
  const float* convb = (const float*)d_in[7];
  const float* gxw   = (const float*)d_in[8];
  const float* gxb   = (const float*)d_in[9];
  const float* gaw   = (const float*)d_in[10];
  const float* gab   = (const float*)d_in[11];
  const float* apar  = (const float*)d_in[12];
  const float* ybias = (const float*)d_in[13];
  const float* Wout  = (const float*)d_in[14];
  const float* bout  = (const float*)d_in[15];

  float* out    = (float*)d_out;
  float* cs_out = out + (size_t)MROWS * WIDTH_;
  float* lh_out = cs_out + (size_t)BB * LRU_ * DCONV_;

  // scratch inside d_out (dead until GEMM3 rewrites the whole out region)
  ushort_t* ybf = (ushort_t*)d_out;                                   // 41.94 MB
  ushort_t* AA  = (ushort_t*)((char*)d_out + (size_t)41943040);       // 41.94 MB

  // workspace layout (159.3 MB total)
  const size_t SZ_BIG = (size_t)MROWS * LRU_ * 2;      // 41,943,040
  const size_t SZ_W   = (size_t)LRU_ * WIDTH_ * 2;     // 13,107,200
  const size_t SZ_GW  = (size_t)HEADS_ * BW_ * BW_ * 2;// 1,638,400
  const size_t SZ_SM  = (size_t)BB * NCH * LRU_ * 4;   // 1,310,720
  size_t need = SZ_BIG * 3 + SZ_W * 2 + SZ_GW * 2 + 10240 + SZ_SM * 3;
  if (ws_size < need) return;  // diagnostic: zero-output signature => ws too small

  char* p = (char*)d_ws;
  ushort_t* xbf    = (ushort_t*)p; p += SZ_BIG;
  ushort_t* wybf   = (ushort_t*)p; p += SZ_W;
  ushort_t* wxbf   = (ushort_t*)p; p += SZ_W;   // reused for Wout after GEMM2
  ushort_t* gxwT   = (ushort_t*)p; p += SZ_GW;
  ushort_t* gawT   = (ushort_t*)p; p += SZ_GW;
  ushort_t* T2     = (ushort_t*)p; p += SZ_BIG; // xl -> GX -> pre
  ushort_t* xcbf   = (ushort_t*)p; p += SZ_BIG;
  float*    ctab   = (float*)p;    p += 10240;
  float*    cA     = (float*)p;    p += SZ_SM;
  float*    cH     = (float*)p;    p += SZ_SM;
  float*    hInit  = (float*)p;    p += SZ_SM;
  ushort_t* woutbf = wxbf;

  const int BLK = 256;
  // convert inputs to bf16
  cvt_bf16x4<<<(MROWS * WIDTH_ / 4 + BLK - 1) / BLK, BLK, 0, stream>>>((const float4*)x, (ushort4*)xbf, MROWS * WIDTH_ / 4);
  cvt_bf16x4<<<(LRU_ * WIDTH_ / 4 + BLK - 1) / BLK, BLK, 0, stream>>>((const float4*)Wy, (ushort4*)wybf, LRU_ * WIDTH_ / 4);
  cvt_bf16x4<<<(LRU_ * WIDTH_ / 4 + BLK - 1) / BLK, BLK, 0, stream>>>((const float4*)Wx, (ushort4*)wxbf, LRU_ * WIDTH_ / 4);

  // xl(bf16) = x @ Wx^T + bx   ;   y(bf16) = x @ Wy^T
  gemm_bt<128, 1><<<dim3(MROWS / 128, WIDTH_ / 128, 1), BLK, 0, stream>>>(
      xbf, WIDTH_, 0, wxbf, 0, T2, LRU_, 0, bx, 0, WIDTH_, nullptr, nullptr, nullptr);
  gemm_bt<128, 1><<<dim3(MROWS / 128, WIDTH_ / 128, 1), BLK, 0, stream>>>(
      xbf, WIDTH_, 0, wybf, 0, ybf, LRU_, 0, nullptr, 0, WIDTH_, nullptr, nullptr, nullptr);

  // Wout conversion into wx's slot (wx dead after GEMM above)
  cvt_bf16x4<<<(WIDTH_ * LRU_ / 4 + BLK - 1) / BLK, BLK, 0, stream>>>((const float4*)Wout, (ushort4*)woutbf, WIDTH_ * LRU_ / 4);

  // conv + conv_state (from bf16 xl in T2)
  conv_kernel<<<(MROWS * LRU_ + BLK - 1) / BLK, BLK, 0, stream>>>(T2, convw, convb, xcbf);
  conv_state_kernel<<<(BB * LRU_ * DCONV_ + BLK - 1) / BLK, BLK, 0, stream>>>(T2, cidx, cs_out);

  // gate weight transposes + per-channel c table
  cvt_transpose<<<(HEADS_ * BW_ * BW_ + BLK - 1) / BLK, BLK, 0, stream>>>(gxw, gxwT, HEADS_ * BW_ * BW_);
  cvt_transpose<<<(HEADS_ * BW_ * BW_ + BLK - 1) / BLK, BLK, 0, stream>>>(gaw, gawT, HEADS_ * BW_ * BW_);
  ctab_kernel<<<(LRU_ + BLK - 1) / BLK, BLK, 0, stream>>>(apar, ctab);

  // gate GEMMs with fused epilogues:
  //   GX = xc * sigmoid(gx+gxb)  -> T2 (overwrites dead xl)
  //   AA = reset?0:exp(c*sigmoid(ga+gab)) -> scratch in d_out
  gemm_bt<64, 2><<<dim3(MROWS / 128, BW_ / 64, HEADS_), BLK, 0, stream>>>(
      xcbf, LRU_, BW_, gxwT, BW_ * BW_, T2, LRU_, BW_, gxb, BW_, BW_, xcbf, nullptr, nullptr);
  gemm_bt<64, 3><<<dim3(MROWS / 128, BW_ / 64, HEADS_), BLK, 0, stream>>>(
      xcbf, LRU_, BW_, gawT, BW_ * BW_, AA, LRU_, BW_, gab, BW_, BW_, nullptr, ctab, seg);

  // chunked scan + fused gelu multiply (pre written in-place over GX in T2)
  scanA<<<(BB * NCH * LRU_ + BLK - 1) / BLK, BLK, 0, stream>>>(AA, T2, cA, cH);
  scanB<<<(BB * LRU_ + BLK - 1) / BLK, BLK, 0, stream>>>(cA, cH, hInit);
  scanC<<<(BB * NCH * LRU_ + BLK - 1) / BLK, BLK, 0, stream>>>(AA, T2, hInit, ybf, ybias, lh_out);

  // out = pre @ Wout^T + bout   (overwrites ybf/AA scratch regions — they're dead)
  gemm_bt<128, 0><<<dim3(MROWS / 128, WIDTH_ / 128, 1), BLK, 0, stream>>>(
      T2, LRU_, 0, woutbf, 0, out, WIDTH_, 0, bout, 0, LRU_, nullptr, nullptr, nullptr);
}

// Round 3
// 685.898 us; speedup vs baseline: 1.0567x; 1.0567x over previous
//
#include <hip/hip_runtime.h>
#include <hip/hip_bf16.h>

#define WIDTH_ 2560
#define LRU_   2560
#define HEADS_ 8
#define BW_    320
#define DCONV_ 4
#define BB     4
#define LL     2048
#define MROWS  (BB*LL)          // 8192
#define NCH    32               // scan chunks
#define CLEN   (LL/NCH)         // 64

typedef unsigned short ushort_t;
typedef __attribute__((ext_vector_type(8))) short short8;
typedef __attribute__((ext_vector_type(4))) float f32x4;

__device__ __forceinline__ unsigned short f2bf(float f) {
  union { float f; unsigned u; } v; v.f = f;
  unsigned r = v.u + 0x7fffu + ((v.u >> 16) & 1u);
  return (unsigned short)(r >> 16);
}
__device__ __forceinline__ float bf2f(unsigned short h) {
  union { unsigned u; float f; } v; v.u = ((unsigned)h) << 16;
  return v.f;
}
__device__ __forceinline__ void async_load16(const void* g, void* l) {
  __builtin_amdgcn_global_load_lds(
      (const __attribute__((address_space(1))) unsigned*)g,
      (__attribute__((address_space(3))) unsigned*)l, 16, 0, 0);
}
__device__ __forceinline__ float sigmoidf_(float x) {
  return 1.f / (1.f + __expf(-x));
}

// ---------------- conversion kernels ----------------
__global__ void cvt_bf16x4(const float4* __restrict__ in, ushort4* __restrict__ out, int n4) {
  int i = blockIdx.x * blockDim.x + threadIdx.x;
  if (i >= n4) return;
  float4 v = in[i];
  ushort4 o;
  o.x = f2bf(v.x); o.y = f2bf(v.y); o.z = f2bf(v.z); o.w = f2bf(v.w);
  out[i] = o;
}

// gwT[h][rowoff + j][i] = w[h][i][j]   (bf16), head stride 640*320
__global__ void cvt_transpose(const float* __restrict__ w, ushort_t* __restrict__ gwT,
                              int rowoff, int n) {
  int i = blockIdx.x * blockDim.x + threadIdx.x;
  if (i >= n) return;
  int ii = i % BW_;
  int j  = (i / BW_) % BW_;
  int h  = i / (BW_ * BW_);
  gwT[((size_t)h * 640 + rowoff + j) * BW_ + ii] = f2bf(w[((size_t)h * BW_ + ii) * BW_ + j]);
}

// ctab[e] = -8 * softplus(a_param[e])
__global__ void ctab_kernel(const float* __restrict__ apar, float* __restrict__ ctab) {
  int e = blockIdx.x * blockDim.x + threadIdx.x;
  if (e >= LRU_) return;
  float ap = apar[e];
  float sp = (ap > 15.f) ? ap : log1pf(expf(ap));
  ctab[e] = -8.f * sp;
}

// ---------------- 8-phase 256x256 GEMM (m201 template, plain HIP) ----------------
// C[M,N] = A[M,2560](bf16) * B[N,2560](bf16)^T ; M=8192, N from grid (x: 32 m-tiles)
// EPI 0: f32 store + bias   EPI 1: split store bf16 (col<2560 -> C0 +bias, else C1)
template<int EPI>
__global__ __launch_bounds__(512, 2)
void gemm8p(const ushort_t* __restrict__ A,
            const ushort_t* __restrict__ B,
            void* __restrict__ C0, void* __restrict__ C1,
            const float* __restrict__ bias) {
  constexpr int LDA = 2560, KK = 2560, NT = KK / 64, MT = 32;
  __shared__ char smem[131072];   // [A|B] x [buf0|buf1] x [half0|half1] x 16KB
  const int tid = threadIdx.x;
  const int lane = tid & 63, w = tid >> 6;
  const int wr = w >> 2, wc = w & 3;
  const int l15 = lane & 15, l4 = lane >> 4;

  // XCD-aware bijective swizzle (gridDim.x % 8 == 0)
  const int nblk = gridDim.x;
  const int bid = blockIdx.x;
  const int swz = (bid & 7) * (nblk >> 3) + (bid >> 3);
  const int tm = (swz % MT) * 256;
  const int tn = (swz / MT) * 256;

  // staging address precompute: linear LDS dest, inverse-swizzled global source
  unsigned aoff[4], boff[4]; int ldst[4];
#pragma unroll
  for (int h = 0; h < 2; ++h)
#pragma unroll
    for (int j = 0; j < 2; ++j) {
      int lb = (j * 512 + tid) * 16;
      int lbl = lb ^ (((lb >> 9) & 1) << 5);     // st_16x32 (involution)
      int row = lbl >> 7, colb = lbl & 127;
      aoff[h * 2 + j] = (unsigned)(tm + h * 128 + row) * (LDA * 2) + colb;
      boff[h * 2 + j] = (unsigned)(tn + h * 128 + row) * (KK * 2) + colb;
      ldst[h * 2 + j] = h * 16384 + lb;
    }

  auto STAGE_A = [&](int kt, int p) {
#pragma unroll
    for (int u = 0; u < 4; ++u)
      async_load16((const char*)A + (size_t)aoff[u] + (unsigned)kt * 128,
                   smem + p * 32768 + ldst[u]);
  };
  auto STAGE_B = [&](int kt, int p) {
#pragma unroll
    for (int u = 0; u < 4; ++u)
      async_load16((const char*)B + (size_t)boff[u] + (unsigned)kt * 128,
                   smem + 65536 + p * 32768 + ldst[u]);
  };
  auto LDFRAG = [&](const char* half, int row, int sbyte) -> short8 {
    int lb = row * 128 + sbyte;
    lb ^= ((lb >> 9) & 1) << 5;                  // swizzled read
    return *(const short8*)(half + lb);
  };

  f32x4 acc[8][4] = {};

  STAGE_A(0, 0); STAGE_B(0, 0);
  asm volatile("s_waitcnt vmcnt(0)" ::: "memory");
  __builtin_amdgcn_s_barrier();

  for (int t = 0; t < NT; ++t) {
    const int p = t & 1;
    const char* Ah = smem + p * 32768 + wr * 16384;
    const char* Bh = smem + 65536 + p * 32768 + (wc >> 1) * 16384;
    const int bcol0 = (wc & 1) * 64;
    short8 bfrag[4][2];
    const bool st = (t + 1 < NT);
#pragma unroll
    for (int q = 0; q < 4; ++q) {
      short8 a[2][2];
#pragma unroll
      for (int mm = 0; mm < 2; ++mm)
#pragma unroll
        for (int s = 0; s < 2; ++s)
          a[mm][s] = LDFRAG(Ah, (2 * q + mm) * 16 + l15, s * 64 + l4 * 16);
      if (q == 0) {
#pragma unroll
        for (int n = 0; n < 4; ++n)
#pragma unroll
          for (int s = 0; s < 2; ++s)
            bfrag[n][s] = LDFRAG(Bh, bcol0 + n * 16 + l15, s * 64 + l4 * 16);
        if (st) STAGE_A(t + 1, p ^ 1);
      }
      if (q == 1 && st) STAGE_B(t + 1, p ^ 1);
      __builtin_amdgcn_s_barrier();
      __builtin_amdgcn_s_setprio(1);
#pragma unroll
      for (int mm = 0; mm < 2; ++mm)
#pragma unroll
        for (int n = 0; n < 4; ++n)
#pragma unroll
          for (int s = 0; s < 2; ++s)
            acc[2 * q + mm][n] = __builtin_amdgcn_mfma_f32_16x16x32_bf16(
                a[mm][s], bfrag[n][s], acc[2 * q + mm][n], 0, 0, 0);
      __builtin_amdgcn_s_setprio(0);
      if (q == 3) asm volatile("s_waitcnt vmcnt(0)" ::: "memory");
      __builtin_amdgcn_s_barrier();
    }
  }

  // epilogue: C row = (lane>>4)*4 + r, col = lane&15
  const int crow0 = tm + wr * 128 + l4 * 4;
  const int ccol0 = tn + wc * 64 + l15;
#pragma unroll
  for (int m = 0; m < 8; ++m)
#pragma unroll
    for (int n = 0; n < 4; ++n) {
      const int col = ccol0 + n * 16;
#pragma unroll
      for (int r = 0; r < 4; ++r) {
        const int row = crow0 + m * 16 + r;
        float v = acc[m][n][r];
        if (EPI == 0) {
          ((float*)C0)[(size_t)row * 2560 + col] = v + bias[col];
        } else {
          if (col < 2560)
            ((ushort_t*)C0)[(size_t)row * 2560 + col] = f2bf(v + bias[col]);
          else
            ((ushort_t*)C1)[(size_t)row * 2560 + (col - 2560)] = f2bf(v);
        }
      }
    }
}

// ---------------- gate GEMM (m97 structure, fused gx+ga epilogue) ----------------
// per head z: C' = xc_head @ gwT_z^T ; gwT_z = [gxw_z^T ; gaw_z^T]  (640 x 320)
__global__ __launch_bounds__(256, 2)
void gate_gemm(const ushort_t* __restrict__ A,      // xcbf [8192][2560]
               const ushort_t* __restrict__ Bw,     // gwT [8][640][320]
               ushort_t* __restrict__ GX,           // T2 [8192][2560]
               ushort_t* __restrict__ AAo,          // AA [8192][2560]
               const float* __restrict__ gxb, const float* __restrict__ gab,
               const float* __restrict__ ctab, const int* __restrict__ seg) {
  constexpr int BM = 128, BN = 64, BK = 32, WTN = 32, NF = 2;
  __shared__ ushort_t lds_a[BM * BK];
  __shared__ ushort_t lds_b[BN * BK];

  const int tid = threadIdx.x;
  const int w = tid >> 6, lane = tid & 63;
  const int wr = w >> 1, wc = w & 1;
  const int tm = blockIdx.x * BM;
  const int tn = blockIdx.y * BN;     // 0..576, region: <320 GX, >=320 AA
  const int z = blockIdx.z;
  const ushort_t* Ab = A + (size_t)z * BW_;
  const ushort_t* Bb = Bw + (size_t)z * 640 * BW_ + (size_t)tn * BW_;

  f32x4 acc[4][NF] = {};
  const int ksub = (lane >> 4) * 8;
  const int rA = wr * 64 + (lane & 15);
  const int rB = wc * WTN + (lane & 15);

  for (int k0 = 0; k0 < BW_; k0 += BK) {
#pragma unroll
    for (int i = 0; i < 2; ++i) {
      int bo = (i * 256 + tid) * 16;
      int row = bo >> 6, colb = bo & 63;
      async_load16((const char*)Ab + (size_t)(tm + row) * LRU_ * 2 + (size_t)k0 * 2 + colb,
                   (char*)lds_a + bo);
    }
    {
      int bo = tid * 16;
      int row = bo >> 6, colb = bo & 63;
      async_load16((const char*)Bb + (size_t)row * BW_ * 2 + (size_t)k0 * 2 + colb,
                   (char*)lds_b + bo);
    }
    __syncthreads();
    short8 af[4], bfr[NF];
#pragma unroll
    for (int mf = 0; mf < 4; ++mf)
      af[mf] = *(const short8*)&lds_a[(rA + mf * 16) * BK + ksub];
#pragma unroll
    for (int nf = 0; nf < NF; ++nf)
      bfr[nf] = *(const short8*)&lds_b[(rB + nf * 16) * BK + ksub];
#pragma unroll
    for (int mf = 0; mf < 4; ++mf)
#pragma unroll
      for (int nf = 0; nf < NF; ++nf)
        acc[mf][nf] = __builtin_amdgcn_mfma_f32_16x16x32_bf16(af[mf], bfr[nf], acc[mf][nf], 0, 0, 0);
    __syncthreads();
  }

  const int crow0 = tm + wr * 64 + ((lane >> 4) << 2);
  const int ccol0 = tn + wc * WTN + (lane & 15);
#pragma unroll
  for (int mf = 0; mf < 4; ++mf) {
#pragma unroll
    for (int nf = 0; nf < NF; ++nf) {
      const int cih = ccol0 + nf * 16;     // 0..639 within head
#pragma unroll
      for (int r = 0; r < 4; ++r) {
        const int row = crow0 + mf * 16 + r;
        if (cih < BW_) {
          const int gc = z * BW_ + cih;
          float v = acc[mf][nf][r] + gxb[gc];
          float xc = bf2f(A[(size_t)row * LRU_ + gc]);
          GX[(size_t)row * LRU_ + gc] = f2bf(xc * sigmoidf_(v));
        } else {
          const int gc = z * BW_ + cih - BW_;
          float v = acc[mf][nf][r] + gab[gc];
          float la = ctab[gc] * sigmoidf_(v);
          float av = (seg[row] == 0) ? 0.f : expf(la);
          AAo[(size_t)row * LRU_ + gc] = f2bf(av);
        }
      }
    }
  }
}

// ---------------- conv (causal depthwise, window 4), bf16, x8 vectorized ----------
__global__ void conv_kernel(const ushort_t* __restrict__ xl, const float* __restrict__ convw,
                            const float* __restrict__ convb, ushort_t* __restrict__ xcbf) {
  int i = blockIdx.x * blockDim.x + threadIdx.x;     // over MROWS*LRU/8
  if (i >= MROWS * LRU_ / 8) return;
  int e0 = (i % (LRU_ / 8)) * 8;
  int t = (i / (LRU_ / 8)) % LL;
  int b = i / ((LRU_ / 8) * LL);
  size_t rowb = ((size_t)b * LL + t) * LRU_;
  const ushort_t* base = xl + rowb + e0;
  short8 v0 = {}, v1 = {}, v2 = {}, v3;
  if (t >= 3) v0 = *(const short8*)(base - 3 * LRU_);
  if (t >= 2) v1 = *(const short8*)(base - 2 * LRU_);
  if (t >= 1) v2 = *(const short8*)(base - 1 * LRU_);
  v3 = *(const short8*)(base);
  ushort_t o[8];
#pragma unroll
  for (int u = 0; u < 8; ++u) {
    float4 wv = ((const float4*)convw)[e0 + u];
    float acc = convb[e0 + u];
    acc += wv.x * bf2f((ushort_t)v0[u]);
    acc += wv.y * bf2f((ushort_t)v1[u]);
    acc += wv.z * bf2f((ushort_t)v2[u]);
    acc += wv.w * bf2f((ushort_t)v3[u]);
    o[u] = f2bf(acc);
  }
  *(short8*)(xcbf + rowb + e0) = *(short8*)o;
}

__global__ void conv_state_kernel(const ushort_t* __restrict__ xl, const int* __restrict__ cidx,
                                  float* __restrict__ cs) {
  int i = blockIdx.x * blockDim.x + threadIdx.x;
  if (i >= BB * LRU_ * DCONV_) return;
  int e = (i / DCONV_) % LRU_;
  int b = i / (DCONV_ * LRU_);
  int idx = cidx[i];
  int ts = idx - (DCONV_ - 1);
  float v = 0.f;
  if (ts >= 0 && ts < LL) v = bf2f(xl[((size_t)b * LL + ts) * LRU_ + e]);
  cs[i] = v;
}

// ---------------- chunked scan ----------------
__global__ void scanA(const ushort_t* __restrict__ AA, const ushort_t* __restrict__ GX,
                      float* __restrict__ cA, float* __restrict__ cH) {
  int i = blockIdx.x * blockDim.x + threadIdx.x;
  if (i >= BB * NCH * LRU_) return;
  int e = i % LRU_;
  int c = (i / LRU_) % NCH;
  int b = i / (LRU_ * NCH);
  float Ap = 1.f, h = 0.f;
  size_t base = ((size_t)b * LL + (size_t)c * CLEN) * LRU_ + e;
  for (int t = 0; t < CLEN; ++t) {
    size_t j = base + (size_t)t * LRU_;
    float a = bf2f(AA[j]);
    float nx = bf2f(GX[j]) * sqrtf(fmaxf(0.f, 1.f - a * a));
    Ap *= a;
    h = a * h + nx;
  }
  cA[i] = Ap; cH[i] = h;
}

__global__ void scanB(const float* __restrict__ cA, const float* __restrict__ cH,
                      float* __restrict__ hInit) {
  int i = blockIdx.x * blockDim.x + threadIdx.x;
  if (i >= BB * LRU_) return;
  int e = i % LRU_;
  int b = i / LRU_;
  float h = 0.f;
  for (int c = 0; c < NCH; ++c) {
    size_t j = ((size_t)b * NCH + c) * LRU_ + e;
    hInit[j] = h;
    h = cA[j] * h + cH[j];
  }
}

__global__ void scanC(const ushort_t* __restrict__ AA, const ushort_t* __restrict__ GXpre,
                      const float* __restrict__ hInit, const ushort_t* __restrict__ ybf,
                      const float* __restrict__ ybias, float* __restrict__ lastH) {
  int i = blockIdx.x * blockDim.x + threadIdx.x;
  if (i >= BB * NCH * LRU_) return;
  int e = i % LRU_;
  int c = (i / LRU_) % NCH;
  int b = i / (LRU_ * NCH);
  float h = hInit[i];
  float yb = ybias[e];
  ushort_t* pre = (ushort_t*)GXpre;
  size_t base = ((size_t)b * LL + (size_t)c * CLEN) * LRU_ + e;
  for (int t = 0; t < CLEN; ++t) {
    size_t j = base + (size_t)t * LRU_;
    float a = bf2f(AA[j]);
    float nx = bf2f(GXpre[j]) * sqrtf(fmaxf(0.f, 1.f - a * a));
    h = a * h + nx;
    float yv = bf2f(ybf[j]) + yb;
    float g = 0.5f * yv * (1.f + erff(yv * 0.70710678118f));
    pre[j] = f2bf(h * g);
  }
  if (c == NCH - 1) lastH[(size_t)b * LRU_ + e] = h;
}

// ---------------- launch ----------------
extern "C" void kernel_launch(void* const* d_in, const int* in_sizes, int n_in,
                              void* d_out, int out_size, void* d_ws, size_t ws_size,
                              hipStream_t stream) {
  const float* x     = (const float*)d_in[0];
  const int*   seg   = (const int*)d_in[1];
  const int*   cidx  = (const int*)d_in[2];
  const float* Wx    = (const float*)d_in[3];
  const float* bx    = (const float*)d_in[4];
  const float* Wy    = (const float*)d_in[5];
  const float* convw = (const float*)d_in[6];
  const float* convb = (const float*)d_in[7];
  const float* gxw   = (const float*)d_in[8];
  const float* gxb   = (const float*)d_in[9];
  const float* gaw   = (const float*)d_in[10];
  const float* gab   = (const float*)d_in[11];
  const float* apar  = (const float*)d_in[12];
  const float* ybias = (const float*)d_in[13];
  const float* Wout  = (const float*)d_in[14];
  const float* bout  = (const float*)d_in[15];

  float* out    = (float*)d_out;
  float* cs_out = out + (size_t)MROWS * WIDTH_;
  float* lh_out = cs_out + (size_t)BB * LRU_ * DCONV_;

  // scratch inside d_out (dead until the final GEMM rewrites the out region)
  ushort_t* ybf = (ushort_t*)d_out;                               // 41.94 MB
  ushort_t* AA  = (ushort_t*)((char*)d_out + (size_t)41943040);   // 41.94 MB

  const size_t SZ_BIG = (size_t)MROWS * LRU_ * 2;       // 41,943,040
  const size_t SZ_WC  = (size_t)(2 * LRU_) * WIDTH_ * 2;// 26,214,400
  const size_t SZ_GW  = (size_t)HEADS_ * 640 * BW_ * 2; // 3,276,800
  const size_t SZ_SM  = (size_t)BB * NCH * LRU_ * 4;    // 1,310,720
  size_t need = SZ_BIG * 3 + SZ_WC + SZ_GW + 10240 + SZ_SM * 3;
  if (ws_size < need) return;

  char* p = (char*)d_ws;
  ushort_t* xbf   = (ushort_t*)p; p += SZ_BIG;
  ushort_t* wcat  = (ushort_t*)p; p += SZ_WC;   // [Wx ; Wy] bf16, later Wout in first half
  ushort_t* T2    = (ushort_t*)p; p += SZ_BIG;  // xl -> GX -> pre
  ushort_t* xcbf  = (ushort_t*)p; p += SZ_BIG;
  ushort_t* gwT   = (ushort_t*)p; p += SZ_GW;   // [8][640][320] = [gxw^T ; gaw^T]
  float*    ctab  = (float*)p;    p += 10240;
  float*    cA    = (float*)p;    p += SZ_SM;
  float*    cH    = (float*)p;    p += SZ_SM;
  float*    hInit = (float*)p;    p += SZ_SM;
  ushort_t* woutbf = wcat;

  const int BLK = 256;
  cvt_bf16x4<<<(MROWS * WIDTH_ / 4 + BLK - 1) / BLK, BLK, 0, stream>>>(
      (const float4*)x, (ushort4*)xbf, MROWS * WIDTH_ / 4);
  cvt_bf16x4<<<(LRU_ * WIDTH_ / 4 + BLK - 1) / BLK, BLK, 0, stream>>>(
      (const float4*)Wx, (ushort4*)wcat, LRU_ * WIDTH_ / 4);
  cvt_bf16x4<<<(LRU_ * WIDTH_ / 4 + BLK - 1) / BLK, BLK, 0, stream>>>(
      (const float4*)Wy, (ushort4*)(wcat + (size_t)LRU_ * WIDTH_), LRU_ * WIDTH_ / 4);

  // fused: [xl | y] = x @ [Wx;Wy]^T   (N=5120, 640 blocks)
  gemm8p<1><<<640, 512, 0, stream>>>(xbf, wcat, T2, ybf, bx);

  // Wout -> first half of wcat (dead after fused GEMM; stream-ordered)
  cvt_bf16x4<<<(WIDTH_ * LRU_ / 4 + BLK - 1) / BLK, BLK, 0, stream>>>(
      (const float4*)Wout, (ushort4*)woutbf, WIDTH_ * LRU_ / 4);

  conv_kernel<<<(MROWS * LRU_ / 8 + BLK - 1) / BLK, BLK, 0, stream>>>(T2, convw, convb, xcbf);
  conv_state_kernel<<<(BB * LRU_ * DCONV_ + BLK - 1) / BLK, BLK, 0, stream>>>(T2, cidx, cs_out);

  cvt_transpose<<<(HEADS_ * BW_ * BW_ + BLK - 1) / BLK, BLK, 0, stream>>>(gxw, gwT, 0, HEADS_ * BW_ * BW_);
  cvt_transpose<<<(HEADS_ * BW_ * BW_ + BLK - 1) / BLK, BLK, 0, stream>>>(gaw, gwT, BW_, HEADS_ * BW_ * BW_);
  ctab_kernel<<<(LRU_ + BLK - 1) / BLK, BLK, 0, stream>>>(apar, ctab);

  // fused gate GEMM: GX -> T2 (over dead xl), AA -> d_out scratch
  gate_gemm<<<dim3(MROWS / 128, 10, HEADS_), BLK, 0, stream>>>(
      xcbf, gwT, T2, AA, gxb, gab, ctab, seg);

  scanA<<<(BB * NCH * LRU_ + BLK - 1) / BLK, BLK, 0, stream>>>(AA, T2, cA, cH);
  scanB<<<(BB * LRU_ + BLK - 1) / BLK, BLK, 0, stream>>>(cA, cH, hInit);
  scanC<<<(BB * NCH * LRU_ + BLK - 1) / BLK, BLK, 0, stream>>>(AA, T2, hInit, ybf, ybias, lh_out);

  // out = pre @ Wout^T + bout  (N=2560, 320 blocks)
  gemm8p<0><<<320, 512, 0, stream>>>(T2, woutbf, out, nullptr, bout);
}